// Round 5
// baseline (536.972 us; speedup 1.0000x reference)
//
#include <hip/hip_runtime.h>
#include <hip/hip_bf16.h>

// Problem constants: n_sents=64, S=512, D=768, E=2000, P=20000, NL=128, H=512, C=3
// Identities exploited:
//   feats@W1 = A1[p1] + A2[p2] + y[p1] - y[p2];  A1=e@W1[0:768], A2=e@W1[768:1536], y=x@W1[1536:]
//   => precompute U = A1 + Y + b1, V = A2 - Y; then h = relu(U[p1] + V[p2])
//   conf = max softmax prob > 0.3 is ALWAYS true (3 classes => max p >= 1/3)
//   3rd iteration's x-update is dead code (loss/logits computed before update)

#define D_DIM 768
#define H_DIM 512
#define NL_DIM 128

// ============ big fused GEMM: [A1|A2|X0] = e_emb @ [W1a|W1b|W_proj] =========
// M=2000, N=1152 (18 segments of 64 cols), K=768.
// 128x64 tile, 8x4 per thread, double-buffered LDS (1 barrier/K-tile),
// split-K=4 with atomicAdd epilogue (targets zero-initialized).
#define FTM 128
#define FTN 64
#define FKB 32
#define FKZ 4                      // K split factor; chunk = 768/4 = 192 = 6 ktiles

__global__ __launch_bounds__(256) void gemm_fused(
    const float* __restrict__ Ag, const float* __restrict__ W1,
    const float* __restrict__ W_proj,
    float* __restrict__ A1, float* __restrict__ A2, float* __restrict__ X0, int M)
{
    __shared__ float As[2][FKB][FTM + 4];   // transposed A; row stride 132 (16B-aligned)
    __shared__ float Bs[2][FKB][FTN];
    int t = threadIdx.x;
    int bx = blockIdx.x;                    // 0..17: output-column segment
    int m0 = blockIdx.y * FTM;
    int kbase = blockIdx.z * (D_DIM / FKZ); // 0,192,384,576
    const float* Bt; float* Ct; int ldb, ldc;
    if (bx < 8)       { Bt = W1 + bx * 64;                           ldb = 512; Ct = A1 + bx * 64;        ldc = 512; }
    else if (bx < 16) { Bt = W1 + (size_t)768 * 512 + (bx - 8) * 64; ldb = 512; Ct = A2 + (bx - 8) * 64;  ldc = 512; }
    else              { Bt = W_proj + (bx - 16) * 64;                ldb = 128; Ct = X0 + (bx - 16) * 64; ldc = 128; }

    int ar  = t >> 3;            // 0..31 (A stage row, +32 per pass)
    int ac4 = (t & 7) * 4;       // 0..28 (A stage k)
    int br  = t >> 4;            // 0..15 (B stage k row, +16 per pass)
    int bc4 = (t & 15) * 4;      // 0..60 (B stage col)
    int tm  = t >> 4;            // compute: rows tm*4..+3 and 64+tm*4..+3
    int tn  = t & 15;            // compute: cols tn*4..+3

    float acc[8][4] = {};
    const int NT = (D_DIM / FKZ) / FKB;     // 6 ktiles
    float4 pa[4], pb[2];

    // ---- prologue: stage ktile 0 into buffer 0 ----
#pragma unroll
    for (int p = 0; p < 4; ++p) {
        int row = m0 + ar + 32 * p;
        pa[p] = (row < M) ? *(const float4*)(Ag + (size_t)row * D_DIM + kbase + ac4)
                          : make_float4(0.f, 0.f, 0.f, 0.f);
    }
#pragma unroll
    for (int p = 0; p < 2; ++p)
        pb[p] = *(const float4*)(Bt + (size_t)(kbase + br + 16 * p) * ldb + bc4);
#pragma unroll
    for (int p = 0; p < 4; ++p) {
        As[0][ac4 + 0][ar + 32 * p] = pa[p].x;
        As[0][ac4 + 1][ar + 32 * p] = pa[p].y;
        As[0][ac4 + 2][ar + 32 * p] = pa[p].z;
        As[0][ac4 + 3][ar + 32 * p] = pa[p].w;
    }
#pragma unroll
    for (int p = 0; p < 2; ++p)
        *(float4*)&Bs[0][br + 16 * p][bc4] = pb[p];
    __syncthreads();

    // ---- main loop: 1 barrier per ktile, loads hidden under compute ----
    for (int kt = 0; kt < NT; ++kt) {
        int b = kt & 1;
        if (kt + 1 < NT) {
            int k0 = kbase + (kt + 1) * FKB;
#pragma unroll
            for (int p = 0; p < 4; ++p) {
                int row = m0 + ar + 32 * p;
                pa[p] = (row < M) ? *(const float4*)(Ag + (size_t)row * D_DIM + k0 + ac4)
                                  : make_float4(0.f, 0.f, 0.f, 0.f);
            }
#pragma unroll
            for (int p = 0; p < 2; ++p)
                pb[p] = *(const float4*)(Bt + (size_t)(k0 + br + 16 * p) * ldb + bc4);
        }
#pragma unroll
        for (int k = 0; k < FKB; ++k) {
            float4 a0 = *(const float4*)&As[b][k][tm * 4];        // 2-way bank alias: free
            float4 a1 = *(const float4*)&As[b][k][64 + tm * 4];
            float4 bv = *(const float4*)&Bs[b][k][tn * 4];
            acc[0][0] += a0.x * bv.x; acc[0][1] += a0.x * bv.y; acc[0][2] += a0.x * bv.z; acc[0][3] += a0.x * bv.w;
            acc[1][0] += a0.y * bv.x; acc[1][1] += a0.y * bv.y; acc[1][2] += a0.y * bv.z; acc[1][3] += a0.y * bv.w;
            acc[2][0] += a0.z * bv.x; acc[2][1] += a0.z * bv.y; acc[2][2] += a0.z * bv.z; acc[2][3] += a0.z * bv.w;
            acc[3][0] += a0.w * bv.x; acc[3][1] += a0.w * bv.y; acc[3][2] += a0.w * bv.z; acc[3][3] += a0.w * bv.w;
            acc[4][0] += a1.x * bv.x; acc[4][1] += a1.x * bv.y; acc[4][2] += a1.x * bv.z; acc[4][3] += a1.x * bv.w;
            acc[5][0] += a1.y * bv.x; acc[5][1] += a1.y * bv.y; acc[5][2] += a1.y * bv.z; acc[5][3] += a1.y * bv.w;
            acc[6][0] += a1.z * bv.x; acc[6][1] += a1.z * bv.y; acc[6][2] += a1.z * bv.z; acc[6][3] += a1.z * bv.w;
            acc[7][0] += a1.w * bv.x; acc[7][1] += a1.w * bv.y; acc[7][2] += a1.w * bv.z; acc[7][3] += a1.w * bv.w;
        }
        if (kt + 1 < NT) {
            int nb = (kt + 1) & 1;     // other buffer: its readers finished last iter
#pragma unroll
            for (int p = 0; p < 4; ++p) {
                As[nb][ac4 + 0][ar + 32 * p] = pa[p].x;
                As[nb][ac4 + 1][ar + 32 * p] = pa[p].y;
                As[nb][ac4 + 2][ar + 32 * p] = pa[p].z;
                As[nb][ac4 + 3][ar + 32 * p] = pa[p].w;
            }
#pragma unroll
            for (int p = 0; p < 2; ++p)
                *(float4*)&Bs[nb][br + 16 * p][bc4] = pb[p];
        }
        __syncthreads();
    }
    // ---- epilogue: accumulate split-K partial into C ----
#pragma unroll
    for (int half = 0; half < 2; ++half) {
#pragma unroll
        for (int i = 0; i < 4; ++i) {
            int row = m0 + half * 64 + tm * 4 + i;
            if (row < M) {
                float* cp = Ct + (size_t)row * ldc + tn * 4;
                atomicAdd(&cp[0], acc[half * 4 + i][0]);
                atomicAdd(&cp[1], acc[half * 4 + i][1]);
                atomicAdd(&cp[2], acc[half * 4 + i][2]);
                atomicAdd(&cp[3], acc[half * 4 + i][3]);
            }
        }
    }
}

// ============ small-GEMM machinery (64x64, 4x4/thread) ======================
#define KB 32
#define TM 64
#define TN 64

struct Smem {
    float As[KB][TM + 4];
    float Bs[KB][TN];
};

__device__ __forceinline__ void tile_gemm(
    const float* __restrict__ A, int lda,
    const float* __restrict__ Bt, int ldb,
    int m0, int M, int K, Smem& sm, float acc[4][4], int t)
{
    int tm = t >> 4, tn = t & 15;
    for (int k0 = 0; k0 < K; k0 += KB) {
#pragma unroll
        for (int r = 0; r < 2; ++r) {
            int row = (t >> 3) + 32 * r;
            int c4 = (t & 7) * 4;
            float4 av = make_float4(0.f, 0.f, 0.f, 0.f);
            if (m0 + row < M)
                av = *(const float4*)(A + (size_t)(m0 + row) * lda + k0 + c4);
            sm.As[c4 + 0][row] = av.x;
            sm.As[c4 + 1][row] = av.y;
            sm.As[c4 + 2][row] = av.z;
            sm.As[c4 + 3][row] = av.w;
        }
#pragma unroll
        for (int r = 0; r < 2; ++r) {
            int row = (t >> 4) + 16 * r;
            int c4 = (t & 15) * 4;
            *(float4*)&sm.Bs[row][c4] =
                *(const float4*)(Bt + (size_t)(k0 + row) * ldb + c4);
        }
        __syncthreads();
#pragma unroll
        for (int k = 0; k < KB; ++k) {
            float4 a = *(const float4*)&sm.As[k][tm * 4];
            float4 b = *(const float4*)&sm.Bs[k][tn * 4];
            acc[0][0] += a.x * b.x; acc[0][1] += a.x * b.y; acc[0][2] += a.x * b.z; acc[0][3] += a.x * b.w;
            acc[1][0] += a.y * b.x; acc[1][1] += a.y * b.y; acc[1][2] += a.y * b.z; acc[1][3] += a.y * b.w;
            acc[2][0] += a.z * b.x; acc[2][1] += a.z * b.y; acc[2][2] += a.z * b.z; acc[2][3] += a.z * b.w;
            acc[3][0] += a.w * b.x; acc[3][1] += a.w * b.y; acc[3][2] += a.w * b.z; acc[3][3] += a.w * b.w;
        }
        __syncthreads();
    }
}

// ---- y = x@W1[1536:], epilogue writes U = A1+y+b1, V = A2-y ---------------
__global__ __launch_bounds__(256) void gemm_y_uv(
    const float* __restrict__ x, const float* __restrict__ W1k,
    const float* __restrict__ A1, const float* __restrict__ A2,
    const float* __restrict__ b1,
    float* __restrict__ U, float* __restrict__ V, int M)
{
    __shared__ Smem sm;
    int t = threadIdx.x;
    int n0 = blockIdx.x * TN;
    int m0 = blockIdx.y * TM;
    float acc[4][4] = {};
    tile_gemm(x, NL_DIM, W1k + n0, H_DIM, m0, M, NL_DIM, sm, acc, t);
    int tm = t >> 4, tn = t & 15;
    float4 b1v = *(const float4*)(b1 + n0 + tn * 4);
#pragma unroll
    for (int i = 0; i < 4; ++i) {
        int row = m0 + tm * 4 + i;
        if (row < M) {
            size_t off = (size_t)row * H_DIM + n0 + tn * 4;
            float4 a1v = *(const float4*)(A1 + off);
            float4 a2v = *(const float4*)(A2 + off);
            float4 u, v;
            u.x = acc[i][0] + a1v.x + b1v.x;  v.x = a2v.x - acc[i][0];
            u.y = acc[i][1] + a1v.y + b1v.y;  v.y = a2v.y - acc[i][1];
            u.z = acc[i][2] + a1v.z + b1v.z;  v.z = a2v.z - acc[i][2];
            u.w = acc[i][3] + a1v.w + b1v.w;  v.w = a2v.w - acc[i][3];
            *(float4*)(U + off) = u;
            *(float4*)(V + off) = v;
        }
    }
}

// ---- xnext = relu(x@W_self + aggI@W_intra + aggE@W_inter) -----------------
__global__ __launch_bounds__(256) void gemm_update3(
    const float* __restrict__ x, const float* __restrict__ aggI, const float* __restrict__ aggE,
    const float* __restrict__ Ws, const float* __restrict__ Wi, const float* __restrict__ We,
    float* __restrict__ xn, int M)
{
    __shared__ Smem sm;
    int t = threadIdx.x;
    int n0 = blockIdx.x * TN;
    int m0 = blockIdx.y * TM;
    float acc[4][4] = {};
    tile_gemm(x,    NL_DIM, Ws + n0, NL_DIM, m0, M, NL_DIM, sm, acc, t);
    tile_gemm(aggI, NL_DIM, Wi + n0, NL_DIM, m0, M, NL_DIM, sm, acc, t);
    tile_gemm(aggE, NL_DIM, We + n0, NL_DIM, m0, M, NL_DIM, sm, acc, t);
    int tm = t >> 4, tn = t & 15;
#pragma unroll
    for (int i = 0; i < 4; ++i) {
        int row = m0 + tm * 4 + i;
        if (row < M)
            *(float4*)(xn + (size_t)row * NL_DIM + n0 + tn * 4) =
                make_float4(fmaxf(acc[i][0], 0.f), fmaxf(acc[i][1], 0.f),
                            fmaxf(acc[i][2], 0.f), fmaxf(acc[i][3], 0.f));
    }
}

// ---- extract events: e_emb[e] = mean of masked token span -----------------
__global__ __launch_bounds__(192) void extract_kernel(
    const float* __restrict__ sent_emb, const int* __restrict__ es,
    const int* __restrict__ st, const int* __restrict__ el,
    float* __restrict__ e_emb)
{
    int e = blockIdx.x;
    int t = threadIdx.x;               // 0..191, one float4 each (768 floats)
    int s = es[e];
    int start = st[e];
    int len = el[e] + 1;               // in [1,8]; start+7 <= 510, no clip needed
    const float* base = sent_emb + ((size_t)s * 512 + start) * D_DIM;
    float4 a = make_float4(0.f, 0.f, 0.f, 0.f);
    for (int k = 0; k < len; ++k) {
        float4 v = ((const float4*)(base + (size_t)k * D_DIM))[t];
        a.x += v.x; a.y += v.y; a.z += v.z; a.w += v.w;
    }
    float inv = 1.0f / (float)len;
    ((float4*)(e_emb + (size_t)e * D_DIM))[t] =
        make_float4(a.x * inv, a.y * inv, a.z * inv, a.w * inv);
}

// ---- zero a float4 region -------------------------------------------------
__global__ __launch_bounds__(256) void zero4_kernel(float4* __restrict__ p, int n4)
{
    int i = blockIdx.x * 256 + threadIdx.x;
    if (i < n4) p[i] = make_float4(0.f, 0.f, 0.f, 0.f);
}

// ---- fused per-pair kernel: 4 waves/block, 4 pairs/wave, batched loads ----
__global__ __launch_bounds__(256) void pair_kernel(
    const float* __restrict__ U, const float* __restrict__ V,
    const float* __restrict__ X, const float* __restrict__ W2,
    const float* __restrict__ b2,
    const int* __restrict__ pair1, const int* __restrict__ pair2,
    const int* __restrict__ rel, const int* __restrict__ tgt,
    float* s_intra, float* s_inter, float* c_intra, float* c_inter,
    float* __restrict__ ce_out, float* logits_out, int P, int do_scatter)
{
    __shared__ float ce_sh[4];
    int t = threadIdx.x;
    int wave = t >> 6;
    int lane = t & 63;
    int base = lane * 8;               // this lane's 8 dims of 512
    float w2f[24];
    {
        const float4* w2p = (const float4*)(W2 + (size_t)base * 3);
#pragma unroll
        for (int q = 0; q < 6; ++q) *(float4*)&w2f[q * 4] = w2p[q];
    }
    float b20 = b2[0], b21 = b2[1], b22 = b2[2];
    int p0 = (blockIdx.x * 4 + wave) * 4;

    // hoist ALL gathers for the wave's 4 pairs: 16 outstanding 16B loads
    int pi1[4], pi2[4];
#pragma unroll
    for (int q = 0; q < 4; ++q) {
        int p = min(p0 + q, P - 1);
        pi1[q] = pair1[p];
        pi2[q] = pair2[p];
    }
    float uf[4][8], vf[4][8];
#pragma unroll
    for (int q = 0; q < 4; ++q) {
        const float4* up = (const float4*)(U + (size_t)pi1[q] * H_DIM + base);
        const float4* vp = (const float4*)(V + (size_t)pi2[q] * H_DIM + base);
        *(float4*)&uf[q][0] = up[0]; *(float4*)&uf[q][4] = up[1];
        *(float4*)&vf[q][0] = vp[0]; *(float4*)&vf[q][4] = vp[1];
    }

    float ce = 0.f;
#pragma unroll
    for (int q = 0; q < 4; ++q) {
        int p = p0 + q;
        if (p >= P) break;
        float l0 = 0.f, l1 = 0.f, l2 = 0.f;
#pragma unroll
        for (int i = 0; i < 8; ++i) {
            float h = fmaxf(uf[q][i] + vf[q][i], 0.f);
            l0 += h * w2f[i * 3 + 0];
            l1 += h * w2f[i * 3 + 1];
            l2 += h * w2f[i * 3 + 2];
        }
#pragma unroll
        for (int off = 32; off > 0; off >>= 1) {
            l0 += __shfl_xor(l0, off);
            l1 += __shfl_xor(l1, off);
            l2 += __shfl_xor(l2, off);
        }
        l0 += b20; l1 += b21; l2 += b22;
        float m = fmaxf(l0, fmaxf(l1, l2));
        float lse = m + logf(expf(l0 - m) + expf(l1 - m) + expf(l2 - m));
        int tg = tgt[p];
        float lt = (tg == 0) ? l0 : ((tg == 1) ? l1 : l2);
        ce += lse - lt;
        if (logits_out && lane == 0) {
            logits_out[(size_t)p * 3 + 0] = l0;
            logits_out[(size_t)p * 3 + 1] = l1;
            logits_out[(size_t)p * 3 + 2] = l2;
        }
        if (do_scatter) {
            int argm = 0; float mx = l0;
            if (l1 > mx) { mx = l1; argm = 1; }
            if (l2 > mx) { mx = l2; argm = 2; }
            if (argm != 0) {
                int r = rel[p];
                int src = (argm == 1) ? pi1[q] : pi2[q];
                int dst = (argm == 1) ? pi2[q] : pi1[q];
                float* sacc = (r == 0) ? s_intra : s_inter;
                float* cacc = (r == 0) ? c_intra : c_inter;
                const float* xs = X + (size_t)src * NL_DIM;
                float* sd = sacc + (size_t)dst * NL_DIM;
                atomicAdd(&sd[lane], xs[lane]);
                atomicAdd(&sd[lane + 64], xs[lane + 64]);
                if (lane == 0) atomicAdd(&cacc[dst], 1.0f);
            }
        }
    }
    if (lane == 0) ce_sh[wave] = ce;
    __syncthreads();
    if (t == 0) ce_out[blockIdx.x] = ce_sh[0] + ce_sh[1] + ce_sh[2] + ce_sh[3];
}

// ---- aggregate: scaled agg_intra / agg_inter ------------------------------
__global__ __launch_bounds__(256) void agg_kernel(
    const float* __restrict__ s_intra, const float* __restrict__ s_inter,
    const float* __restrict__ c_intra, const float* __restrict__ c_inter,
    const float* __restrict__ X,
    float* __restrict__ aggI, float* __restrict__ aggE, int n)
{
    int i = blockIdx.x * 256 + threadIdx.x;
    if (i >= n) return;
    int e = i >> 7;
    float ci = c_intra[e] + 1.0f;
    float cf = fmaxf(c_inter[e], 1.0f);
    aggI[i] = 0.7f * (s_intra[i] + X[i]) / ci;   // BETA_INTRA * agg_intra
    aggE[i] = 0.3f * s_inter[i] / cf;            // BETA_INTER * agg_inter
}

// ---- final deterministic loss reduce --------------------------------------
__global__ __launch_bounds__(256) void loss_kernel(
    const float* __restrict__ ce, int nblk, int P, float* __restrict__ out)
{
    int t = threadIdx.x;
    float acc = 0.f;
    for (int it = 0; it < 3; ++it) {
        float w = 1.0f / ((float)P * (float)(it + 1));
        for (int i = t; i < nblk; i += 256)
            acc += ce[(size_t)it * nblk + i] * w;
    }
    __shared__ float red[256];
    red[t] = acc;
    __syncthreads();
    for (int s = 128; s > 0; s >>= 1) {
        if (t < s) red[t] += red[t + s];
        __syncthreads();
    }
    if (t == 0) out[0] = red[0];
}

extern "C" void kernel_launch(void* const* d_in, const int* in_sizes, int n_in,
                              void* d_out, int out_size, void* d_ws, size_t ws_size,
                              hipStream_t stream)
{
    const float* sent_emb  = (const float*)d_in[0];
    const float* W_proj    = (const float*)d_in[1];
    const float* W1        = (const float*)d_in[2];
    const float* b1        = (const float*)d_in[3];
    const float* W2        = (const float*)d_in[4];
    const float* b2        = (const float*)d_in[5];
    const float* W_self    = (const float*)d_in[6];
    const float* W_intra   = (const float*)d_in[7];
    const float* W_inter   = (const float*)d_in[8];
    const int* event_sent  = (const int*)d_in[9];
    const int* event_start = (const int*)d_in[10];
    const int* event_len   = (const int*)d_in[11];
    const int* pair1       = (const int*)d_in[12];
    const int* pair2       = (const int*)d_in[13];
    const int* rel_type    = (const int*)d_in[14];
    const int* target      = (const int*)d_in[15];

    int E = in_sizes[9];    // 2000
    int P = in_sizes[12];   // 20000
    float* out = (float*)d_out;
    float* ws  = (float*)d_ws;

    // workspace layout. A1|A2|X0 contiguous (one zero pass for atomics).
    size_t o = 0;
    float* e_emb   = ws + o; o += (size_t)E * D_DIM;    // 2000x768 (dead after gemm_fused)
    float* A1      = ws + o; o += (size_t)E * H_DIM;    // | zeroed, atomic targets
    float* A2      = ws + o; o += (size_t)E * H_DIM;    // |
    float* X0      = ws + o; o += (size_t)E * NL_DIM;   // |
    float* V       = ws + o; o += (size_t)E * H_DIM;
    float* X1      = ws + o; o += (size_t)E * NL_DIM;
    float* s_intra = ws + o; o += (size_t)E * NL_DIM;   // | contiguous zero region
    float* s_inter = ws + o; o += (size_t)E * NL_DIM;   // |
    float* c_intra = ws + o; o += (size_t)E;            // |
    float* c_inter = ws + o; o += (size_t)E;            // |
    float* aggI    = ws + o; o += (size_t)E * NL_DIM;
    float* aggE    = ws + o; o += (size_t)E * NL_DIM;
    int NBLK = (P + 15) / 16;                           // 1250
    float* ceb     = ws + o; o += (size_t)3 * NBLK;
    float* U       = e_emb;                             // alias: E*512 <= E*768

    // 1) zero split-K targets; event embeddings
    int cz4 = E * (H_DIM * 2 + NL_DIM) / 4;             // A1,A2,X0 = E*1152 floats
    zero4_kernel<<<(cz4 + 255) / 256, 256, 0, stream>>>((float4*)A1, cz4);
    extract_kernel<<<E, 192, 0, stream>>>(sent_emb, event_sent, event_start, event_len, e_emb);

    // 2) big fused GEMM, split-K=4
    dim3 gF(18, (E + FTM - 1) / FTM, FKZ);              // 18 x 16 x 4 = 1152 blocks
    gemm_fused<<<gF, 256, 0, stream>>>(e_emb, W1, W_proj, A1, A2, X0, E);

    const float* W1k = W1 + (size_t)2 * D_DIM * H_DIM;  // rows 1536..1663
    dim3 gY(H_DIM / TN, (E + TM - 1) / TM);             // 8 x 32
    dim3 gU(NL_DIM / TN, (E + TM - 1) / TM);            // 2 x 32
    float* xcur = X0;
    float* xnext = X1;
    int zn4 = (E * NL_DIM * 2 + E * 2) / 4;
    for (int it = 0; it < 3; ++it) {
        int last = (it == 2);
        gemm_y_uv<<<gY, 256, 0, stream>>>(xcur, W1k, A1, A2, b1, U, V, E);
        if (!last)
            zero4_kernel<<<(zn4 + 255) / 256, 256, 0, stream>>>((float4*)s_intra, zn4);
        pair_kernel<<<NBLK, 256, 0, stream>>>(U, V, xcur, W2, b2,
                                              pair1, pair2, rel_type, target,
                                              s_intra, s_inter, c_intra, c_inter,
                                              ceb + (size_t)it * NBLK,
                                              last ? (out + 1) : nullptr, P, !last);
        if (!last) {
            agg_kernel<<<(E * NL_DIM + 255) / 256, 256, 0, stream>>>(
                s_intra, s_inter, c_intra, c_inter, xcur, aggI, aggE, E * NL_DIM);
            gemm_update3<<<gU, 256, 0, stream>>>(xcur, aggI, aggE, W_self, W_intra, W_inter, xnext, E);
            float* tmp = xcur; xcur = xnext; xnext = tmp;
        }
    }
    loss_kernel<<<1, 256, 0, stream>>>(ceb, NBLK, P, out);
}